// Round 7
// baseline (1317.947 us; speedup 1.0000x reference)
//
#include <hip/hip_runtime.h>
#include <math.h>

#define NN 50000
#define NE 1600000
#define H  64

#define SHIFT 7                 // 128 nodes per bucket
#define NPBKT 128
#define NB    391               // ceil(50000/128)
#define CHUNK 4096
#define NCH   391               // ceil(NE/CHUNK)

typedef __attribute__((ext_vector_type(8))) short s16v8;   // 8 bf16
typedef __attribute__((ext_vector_type(4))) float f32v4;   // MFMA acc
typedef unsigned short u16;
typedef unsigned int   u32;

__device__ __forceinline__ u16 f2bf(float x) {             // RNE f32->bf16
    union { float f; unsigned u; } v; v.f = x;
    unsigned r = v.u + 0x7FFF + ((v.u >> 16) & 1);
    return (u16)(r >> 16);
}
__device__ __forceinline__ float bf2f(u16 h) {
    union { float f; unsigned u; } v; v.u = ((unsigned)h) << 16; return v.f;
}

// ============ CSR build, bucketized ============
__global__ __launch_bounds__(256) void hist_kernel(const int* __restrict__ dst,
                                                   int* __restrict__ chunkhist) {
    __shared__ int h[NB];
    const int c = blockIdx.x;
    for (int b = threadIdx.x; b < NB; b += 256) h[b] = 0;
    __syncthreads();
    const int e0 = c * CHUNK, e1 = min(NE, e0 + CHUNK);
    for (int e = e0 + threadIdx.x; e < e1; e += 256)
        atomicAdd(&h[dst[e] >> SHIFT], 1);
    __syncthreads();
    for (int b = threadIdx.x; b < NB; b += 256)
        chunkhist[c * NB + b] = h[b];
}

__global__ __launch_bounds__(512) void cscan_kernel(int* __restrict__ chunkhist,
                                                    int* __restrict__ bbase) {
    __shared__ int s[512];
    const int t = threadIdx.x;
    int tot = 0;
    if (t < NB)
        for (int c = 0; c < NCH; ++c) tot += chunkhist[c * NB + t];
    s[t] = (t < NB) ? tot : 0;
    __syncthreads();
    for (int d = 1; d < 512; d <<= 1) {
        int v = (t >= d) ? s[t - d] : 0;
        __syncthreads();
        s[t] += v;
        __syncthreads();
    }
    if (t < NB) {
        int base = s[t] - tot;             // exclusive
        bbase[t] = base;
        if (t == NB - 1) bbase[NB] = s[t];
        int run = base;
        for (int c = 0; c < NCH; ++c) {
            int tmp = chunkhist[c * NB + t];
            chunkhist[c * NB + t] = run;
            run += tmp;
        }
    }
}

__global__ __launch_bounds__(256) void scat_kernel(const int* __restrict__ src,
                                                   const int* __restrict__ dst,
                                                   const int* __restrict__ chunkhist,
                                                   u32* __restrict__ bin) {
    __shared__ int base[NB];
    __shared__ int cur[NB];
    const int c = blockIdx.x;
    for (int b = threadIdx.x; b < NB; b += 256) {
        base[b] = chunkhist[c * NB + b];
        cur[b] = 0;
    }
    __syncthreads();
    const int e0 = c * CHUNK, e1 = min(NE, e0 + CHUNK);
    for (int e = e0 + threadIdx.x; e < e1; e += 256) {
        int d = dst[e];
        int b = d >> SHIFT;
        int p = atomicAdd(&cur[b], 1);
        bin[base[b] + p] = (u32)src[e] | ((u32)(d & (NPBKT - 1)) << 16);
    }
}

__global__ __launch_bounds__(256) void binB_kernel(const u32* __restrict__ bin,
                                                   const int* __restrict__ bbase,
                                                   int* __restrict__ off,
                                                   u16* __restrict__ csr) {
    __shared__ int deg[NPBKT];
    __shared__ int sc[NPBKT];
    __shared__ int cur[NPBKT];
    const int b = blockIdx.x, t = threadIdx.x;
    const int seg0 = bbase[b], seg1 = bbase[b + 1];
    if (t < NPBKT) { deg[t] = 0; cur[t] = 0; }
    __syncthreads();
    for (int i = seg0 + t; i < seg1; i += 256)
        atomicAdd(&deg[(bin[i] >> 16) & (NPBKT - 1)], 1);
    __syncthreads();
    if (t < NPBKT) sc[t] = deg[t];
    __syncthreads();
    for (int d = 1; d < NPBKT; d <<= 1) {
        int v = 0;
        if (t < NPBKT && t >= d) v = sc[t - d];
        __syncthreads();
        if (t < NPBKT) sc[t] += v;
        __syncthreads();
    }
    if (t < NPBKT) {
        sc[t] -= deg[t];
        int node = b * NPBKT + t;
        if (node < NN) off[node] = seg0 + sc[t];
        if (b == 0 && t == 0) off[NN] = NE;
    }
    __syncthreads();
    for (int i = seg0 + t; i < seg1; i += 256) {
        u32 e = bin[i];
        int n = (e >> 16) & (NPBKT - 1);
        int p = atomicAdd(&cur[n], 1);
        csr[seg0 + sc[n] + p] = (u16)(e & 0xFFFF);
    }
}

// ============ weight prep: transpose + split into bf16 hi/lo planes ======
__global__ __launch_bounds__(256) void prep_kernel(const float* __restrict__ W1,
        const float* __restrict__ W2, const float* __restrict__ W3,
        u16* __restrict__ wt) {
    int idx = blockIdx.x * 256 + threadIdx.x;
    if (idx >= 2 * 40960) return;
    int b = idx / 40960, r = idx - b * 40960;
    float v; int hioff, losz;
    if (r < 16384) {
        int col = r >> 7, k = r & 127;
        v = W1[b * 24576 + k * 128 + col];
        hioff = b * 81920 + r; losz = 16384;
    } else if (r < 32768) {
        int rr = r - 16384; int col = rr >> 7, k = rr & 127;
        v = W2[b * 16384 + k * 128 + col];
        hioff = b * 81920 + 32768 + rr; losz = 16384;
    } else {
        int rr = r - 32768; int col = rr >> 7, k = rr & 127;
        v = W3[b * 8192 + k * 64 + col];
        hioff = b * 81920 + 65536 + rr; losz = 8192;
    }
    u16 hi = f2bf(v);
    u16 lo = f2bf(v - bf2f(hi));
    wt[hioff] = hi; wt[hioff + losz] = lo;
}

// ============ grep partials (no atomics) ============
__global__ __launch_bounds__(256) void grep_kernel(const float* __restrict__ h,
                                                   float* __restrict__ partial) {
    const int c  = threadIdx.x & 63;
    const int rl = threadIdx.x >> 6;
    float acc = 0.f;
    for (int r = blockIdx.x * 4 + rl; r < NN; r += gridDim.x * 4)
        acc += h[r * H + c];
    __shared__ float s[4][64];
    s[rl][c] = acc;
    __syncthreads();
    if (threadIdx.x < 64)
        partial[blockIdx.x * 64 + threadIdx.x] =
            s[0][threadIdx.x] + s[1][threadIdx.x] +
            s[2][threadIdx.x] + s[3][threadIdx.x];
}

// ============ b1e: reduce partials + fold grep term into layer-1 bias ====
__global__ __launch_bounds__(256) void b1e_kernel(const float* __restrict__ partial,
        const float* __restrict__ W1, const float* __restrict__ b1,
        float* __restrict__ b1e) {
    __shared__ float sg[4][64];
    __shared__ float g[64];
    const int t = threadIdx.x;
    const int c = t & 63, rl = t >> 6;
    float s = 0.f;
    for (int i = rl; i < 256; i += 4) s += partial[i * 64 + c];
    sg[rl][c] = s;
    __syncthreads();
    if (t < 64) g[t] = sg[0][t] + sg[1][t] + sg[2][t] + sg[3][t];
    __syncthreads();
    if (t < 128) {
        float s2 = b1[t];
        for (int k = 0; k < 64; ++k)
            s2 = fmaf(g[k], W1[(128 + k) * 128 + t], s2);
        b1e[t] = s2;
    }
}

// ============ gather: 8 edge-chains per wave, csr batch prefetch ============
__global__ __launch_bounds__(256) void gather_kernel(const float* __restrict__ h,
                                                     const u16* __restrict__ csr,
                                                     const int* __restrict__ off,
                                                     float* __restrict__ agg) {
    const int wid = blockIdx.x * 4 + (threadIdx.x >> 6);
    if (wid >= NN) return;
    const int lane = threadIdx.x & 63;
    const int g8 = lane >> 3, sub = lane & 7;
    const int beg = off[wid], end = off[wid + 1];
    float4 a0 = {0.f, 0.f, 0.f, 0.f}, a1 = {0.f, 0.f, 0.f, 0.f};
    for (int base = beg; base < end; base += 64) {
        const int bcnt = min(64, end - base);
        int ce = (lane < bcnt) ? (int)csr[base + lane] : 0;
#pragma unroll
        for (int r = 0; r < 8; ++r) {
            const int idx = r * 8 + g8;
            const int s = __shfl(ce, min(idx, 63));   // uniform-active shfl
            if (idx < bcnt) {
                const float* hp = h + (size_t)s * 64 + sub * 8;
                float4 v0 = *(const float4*)hp;
                float4 v1 = *(const float4*)(hp + 4);
                a0.x += v0.x; a0.y += v0.y; a0.z += v0.z; a0.w += v0.w;
                a1.x += v1.x; a1.y += v1.y; a1.z += v1.z; a1.w += v1.w;
            }
        }
    }
#pragma unroll
    for (int o = 8; o <= 32; o <<= 1) {
        a0.x += __shfl_xor(a0.x, o); a0.y += __shfl_xor(a0.y, o);
        a0.z += __shfl_xor(a0.z, o); a0.w += __shfl_xor(a0.w, o);
        a1.x += __shfl_xor(a1.x, o); a1.y += __shfl_xor(a1.y, o);
        a1.z += __shfl_xor(a1.z, o); a1.w += __shfl_xor(a1.w, o);
    }
    if (g8 == 0) {
        *(float4*)&agg[(size_t)wid * 64 + sub * 8] = a0;
        *(float4*)&agg[(size_t)wid * 64 + sub * 8 + 4] = a1;
    }
}

// ============ swapped-operand barrier-free MFMA MLP ============
// D = W^T · X^T : node index rides the C-layout column (lane&15), so each
// layer's output is already lane-aligned for the next layer's B-fragment.
// LDS holds only w1hi+w2hi (64 KB, XOR-swizzled); lo planes + w3 stream
// from L2. After the fill barrier, waves are fully independent: grid-stride
// over 16-node strips (3125 strips / 2048 waves).
#define MLP_MFMA(d, a, b) d = __builtin_amdgcn_mfma_f32_16x16x32_bf16(a, b, d, 0, 0, 0)

__global__ __launch_bounds__(256, 2) void mlp_mfma(
    const float* __restrict__ agg, const float* __restrict__ hin,
    const float* __restrict__ b1e, const u16* __restrict__ wt,
    const float* __restrict__ b2, const float* __restrict__ b3,
    float* __restrict__ out)
{
    __shared__ u16 lw[32768];            // [0]=w1hi swz, [16384]=w2hi swz
    const int t = threadIdx.x;
    for (int i = t; i < 4096; i += 256) {
        const int plane = i >> 11, r = i & 2047;
        const int col = r >> 4, kb = r & 15;
        s16v8 v = *(const s16v8*)(wt + plane * 32768 + col * 128 + kb * 8);
        const int slot = (kb & 8) | ((kb ^ col) & 7);
        *(s16v8*)&lw[plane * 16384 + col * 128 + slot * 8] = v;
    }
    __syncthreads();

    const u16* w1lo = wt + 16384;
    const u16* w2lo = wt + 49152;
    const u16* w3hi = wt + 65536;
    const u16* w3lo = wt + 73728;

    const int lane = t & 63, nd = lane & 15, g = lane >> 4;
    const int wv = blockIdx.x * 4 + (t >> 6);

    for (int s = wv; s < 3125; s += 2048) {
        const int n0 = s * 16;

        // ---- x B-frags: lane nd holds node n0+nd, k-chunk g*8 per ks ----
        s16v8 xh[4], xl[4];
#pragma unroll
        for (int ks = 0; ks < 4; ++ks) {
            const float* sp = ((ks < 2) ? agg : hin) +
                              (size_t)(n0 + nd) * 64 + (ks & 1) * 32 + g * 8;
            float4 u0 = *(const float4*)sp;
            float4 u1 = *(const float4*)(sp + 4);
            float f[8] = {u0.x, u0.y, u0.z, u0.w, u1.x, u1.y, u1.z, u1.w};
#pragma unroll
            for (int j = 0; j < 8; ++j) {
                u16 hb = f2bf(f[j]);
                xh[ks][j] = (short)hb;
                xl[ks][j] = (short)f2bf(f[j] - bf2f(hb));
            }
        }

        // ---- L1: acc[ct] = W1^T(tile ct) · x ----
        f32v4 acc[8];
#pragma unroll
        for (int i = 0; i < 8; ++i) acc[i] = (f32v4){0.f, 0.f, 0.f, 0.f};
#pragma unroll
        for (int ct = 0; ct < 8; ++ct) {
            const int col = ct * 16 + nd;
#pragma unroll
            for (int ks = 0; ks < 4; ++ks) {
                const int kb = ks * 4 + g;
                const int slot = (kb & 8) | ((kb ^ col) & 7);
                s16v8 Ah = *(const s16v8*)&lw[col * 128 + slot * 8];
                s16v8 Al = *(const s16v8*)(w1lo + col * 128 + kb * 8);
                MLP_MFMA(acc[ct], Ah, xh[ks]);
                MLP_MFMA(acc[ct], Ah, xl[ks]);
                MLP_MFMA(acc[ct], Al, xh[ks]);
            }
        }
        float h1[8][4];
#pragma unroll
        for (int ct = 0; ct < 8; ++ct) {
            float4 bb = *(const float4*)&b1e[ct * 16 + g * 4];
            h1[ct][0] = fmaxf(acc[ct][0] + bb.x, 0.f);
            h1[ct][1] = fmaxf(acc[ct][1] + bb.y, 0.f);
            h1[ct][2] = fmaxf(acc[ct][2] + bb.z, 0.f);
            h1[ct][3] = fmaxf(acc[ct][3] + bb.w, 0.f);
        }

        // ---- transform h1 (C-layout) -> B-frags via static double-shfl ----
        s16v8 yh[4], yl[4];
#pragma unroll
        for (int ks = 0; ks < 4; ++ks) {
            float f[8];
#pragma unroll
            for (int jh = 0; jh < 2; ++jh) {
                const int srcl = nd + 16 * ((g * 2 + jh) & 3);
#pragma unroll
                for (int js = 0; js < 4; ++js) {
                    float v0 = __shfl(h1[ks * 2][js], srcl);
                    float v1 = __shfl(h1[ks * 2 + 1][js], srcl);
                    f[jh * 4 + js] = (g >> 1) ? v1 : v0;
                }
            }
#pragma unroll
            for (int j = 0; j < 8; ++j) {
                u16 hb = f2bf(f[j]);
                yh[ks][j] = (short)hb;
                yl[ks][j] = (short)f2bf(f[j] - bf2f(hb));
            }
        }

        // ---- L2 ----
        f32v4 acc2[8];
#pragma unroll
        for (int i = 0; i < 8; ++i) acc2[i] = (f32v4){0.f, 0.f, 0.f, 0.f};
#pragma unroll
        for (int ct = 0; ct < 8; ++ct) {
            const int col = ct * 16 + nd;
#pragma unroll
            for (int ks = 0; ks < 4; ++ks) {
                const int kb = ks * 4 + g;
                const int slot = (kb & 8) | ((kb ^ col) & 7);
                s16v8 Ah = *(const s16v8*)&lw[16384 + col * 128 + slot * 8];
                s16v8 Al = *(const s16v8*)(w2lo + col * 128 + kb * 8);
                MLP_MFMA(acc2[ct], Ah, yh[ks]);
                MLP_MFMA(acc2[ct], Ah, yl[ks]);
                MLP_MFMA(acc2[ct], Al, yh[ks]);
            }
        }
        float h2[8][4];
#pragma unroll
        for (int ct = 0; ct < 8; ++ct) {
            float4 bb = *(const float4*)&b2[ct * 16 + g * 4];
            h2[ct][0] = fmaxf(acc2[ct][0] + bb.x, 0.f);
            h2[ct][1] = fmaxf(acc2[ct][1] + bb.y, 0.f);
            h2[ct][2] = fmaxf(acc2[ct][2] + bb.z, 0.f);
            h2[ct][3] = fmaxf(acc2[ct][3] + bb.w, 0.f);
        }

        s16v8 zh[4], zl[4];
#pragma unroll
        for (int ks = 0; ks < 4; ++ks) {
            float f[8];
#pragma unroll
            for (int jh = 0; jh < 2; ++jh) {
                const int srcl = nd + 16 * ((g * 2 + jh) & 3);
#pragma unroll
                for (int js = 0; js < 4; ++js) {
                    float v0 = __shfl(h2[ks * 2][js], srcl);
                    float v1 = __shfl(h2[ks * 2 + 1][js], srcl);
                    f[jh * 4 + js] = (g >> 1) ? v1 : v0;
                }
            }
#pragma unroll
            for (int j = 0; j < 8; ++j) {
                u16 hb = f2bf(f[j]);
                zh[ks][j] = (short)hb;
                zl[ks][j] = (short)f2bf(f[j] - bf2f(hb));
            }
        }

        // ---- L3 (weights from L2) + row L2 norm + store ----
        f32v4 acc3[4];
#pragma unroll
        for (int i = 0; i < 4; ++i) acc3[i] = (f32v4){0.f, 0.f, 0.f, 0.f};
#pragma unroll
        for (int ct = 0; ct < 4; ++ct) {
            const int col = ct * 16 + nd;
#pragma unroll
            for (int ks = 0; ks < 4; ++ks) {
                const int kb = ks * 4 + g;
                s16v8 Ah = *(const s16v8*)(w3hi + col * 128 + kb * 8);
                s16v8 Al = *(const s16v8*)(w3lo + col * 128 + kb * 8);
                MLP_MFMA(acc3[ct], Ah, zh[ks]);
                MLP_MFMA(acc3[ct], Ah, zl[ks]);
                MLP_MFMA(acc3[ct], Al, zh[ks]);
            }
        }
        float v[4][4];
        float ss = 0.f;
#pragma unroll
        for (int ct = 0; ct < 4; ++ct) {
            float4 bb = *(const float4*)&b3[ct * 16 + g * 4];
            v[ct][0] = acc3[ct][0] + bb.x;
            v[ct][1] = acc3[ct][1] + bb.y;
            v[ct][2] = acc3[ct][2] + bb.z;
            v[ct][3] = acc3[ct][3] + bb.w;
#pragma unroll
            for (int j = 0; j < 4; ++j) ss = fmaf(v[ct][j], v[ct][j], ss);
        }
        ss += __shfl_xor(ss, 16);
        ss += __shfl_xor(ss, 32);
        const float inv = rsqrtf(ss);
        float* op = out + (size_t)(n0 + nd) * 64 + g * 4;
#pragma unroll
        for (int ct = 0; ct < 4; ++ct)
#pragma unroll
            for (int j = 0; j < 4; ++j)
                op[ct * 16 + j] = v[ct][j] * inv;
    }
}

// -------------------------------------------------------------------------
extern "C" void kernel_launch(void* const* d_in, const int* in_sizes, int n_in,
                              void* d_out, int out_size, void* d_ws, size_t ws_size,
                              hipStream_t stream) {
    const float* hidden = (const float*)d_in[0];
    const int*   src    = (const int*)d_in[1];
    const int*   dst    = (const int*)d_in[2];
    const float* W1f    = (const float*)d_in[3];
    const float* b1f    = (const float*)d_in[4];
    const float* W2f    = (const float*)d_in[5];
    const float* b2f    = (const float*)d_in[6];
    const float* W3f    = (const float*)d_in[7];
    const float* b3f    = (const float*)d_in[8];

    float* agg     = (float*)d_ws;                        // NN*H
    float* b1e     = agg + (size_t)NN * H;                // 128
    float* partial = b1e + 128;                           // 256*64
    float* hA      = partial + 256 * 64;                  // NN*H
    int*   bbase   = (int*)(hA + (size_t)NN * H);         // NB+1
    int*   off     = bbase + (NB + 1);                    // NN+1
    int*   chist   = off + (NN + 1);                      // NCH*NB
    u32*   bin     = (u32*)(chist + NCH * NB);            // NE
    u16*   csr     = (u16*)(bin + NE);                    // NE
    u16*   wt      = (u16*)(((uintptr_t)(csr + NE) + 255) & ~(uintptr_t)255);

    // ---- one-time per call: bucketized CSR + weight planes ----
    hist_kernel<<<NCH, 256, 0, stream>>>(dst, chist);
    cscan_kernel<<<1, 512, 0, stream>>>(chist, bbase);
    scat_kernel<<<NCH, 256, 0, stream>>>(src, dst, chist, bin);
    binB_kernel<<<NB, 256, 0, stream>>>(bin, bbase, off, csr);
    prep_kernel<<<(2 * 40960 + 255) / 256, 256, 0, stream>>>(W1f, W2f, W3f, wt);

    const float* hin = hidden;
    float* houts[4] = { hA, (float*)d_out, hA, (float*)d_out };

    for (int it = 0; it < 4; ++it) {
        const int blk = it >> 1;
        grep_kernel<<<256, 256, 0, stream>>>(hin, partial);
        b1e_kernel<<<1, 256, 0, stream>>>(partial, W1f + blk * 24576, b1f + blk * 128, b1e);
        gather_kernel<<<(NN + 3) / 4, 256, 0, stream>>>(hin, csr, off, agg);
        mlp_mfma<<<512, 256, 0, stream>>>(agg, hin, b1e, wt + blk * 81920,
            b2f + blk * 128, b3f + blk * 64, houts[it]);
        hin = houts[it];
    }
}

// Round 8
// 684.082 us; speedup vs baseline: 1.9266x; 1.9266x over previous
//
#include <hip/hip_runtime.h>
#include <math.h>

#define NN 50000
#define NE 1600000
#define H  64

#define SHIFT 7                 // 128 nodes per bucket
#define NPBKT 128
#define NB    391               // ceil(50000/128)
#define CHUNK 4096
#define NCH   391               // ceil(NE/CHUNK)

typedef __attribute__((ext_vector_type(8))) short s16v8;   // 8 bf16
typedef __attribute__((ext_vector_type(4))) float f32v4;   // MFMA acc
typedef unsigned short u16;
typedef unsigned int   u32;

__device__ __forceinline__ u16 f2bf(float x) {             // RNE f32->bf16
    union { float f; unsigned u; } v; v.f = x;
    unsigned r = v.u + 0x7FFF + ((v.u >> 16) & 1);
    return (u16)(r >> 16);
}
__device__ __forceinline__ float bf2f(u16 h) {
    union { float f; unsigned u; } v; v.u = ((unsigned)h) << 16; return v.f;
}

// ============ CSR build, bucketized ============
__global__ __launch_bounds__(256) void hist_kernel(const int* __restrict__ dst,
                                                   int* __restrict__ chunkhist) {
    __shared__ int h[NB];
    const int c = blockIdx.x;
    for (int b = threadIdx.x; b < NB; b += 256) h[b] = 0;
    __syncthreads();
    const int e0 = c * CHUNK, e1 = min(NE, e0 + CHUNK);
    for (int e = e0 + threadIdx.x; e < e1; e += 256)
        atomicAdd(&h[dst[e] >> SHIFT], 1);
    __syncthreads();
    for (int b = threadIdx.x; b < NB; b += 256)
        chunkhist[c * NB + b] = h[b];
}

__global__ __launch_bounds__(512) void cscan_kernel(int* __restrict__ chunkhist,
                                                    int* __restrict__ bbase) {
    __shared__ int s[512];
    const int t = threadIdx.x;
    int tot = 0;
    if (t < NB)
        for (int c = 0; c < NCH; ++c) tot += chunkhist[c * NB + t];
    s[t] = (t < NB) ? tot : 0;
    __syncthreads();
    for (int d = 1; d < 512; d <<= 1) {
        int v = (t >= d) ? s[t - d] : 0;
        __syncthreads();
        s[t] += v;
        __syncthreads();
    }
    if (t < NB) {
        int base = s[t] - tot;             // exclusive
        bbase[t] = base;
        if (t == NB - 1) bbase[NB] = s[t];
        int run = base;
        for (int c = 0; c < NCH; ++c) {
            int tmp = chunkhist[c * NB + t];
            chunkhist[c * NB + t] = run;
            run += tmp;
        }
    }
}

__global__ __launch_bounds__(256) void scat_kernel(const int* __restrict__ src,
                                                   const int* __restrict__ dst,
                                                   const int* __restrict__ chunkhist,
                                                   u32* __restrict__ bin) {
    __shared__ int base[NB];
    __shared__ int cur[NB];
    const int c = blockIdx.x;
    for (int b = threadIdx.x; b < NB; b += 256) {
        base[b] = chunkhist[c * NB + b];
        cur[b] = 0;
    }
    __syncthreads();
    const int e0 = c * CHUNK, e1 = min(NE, e0 + CHUNK);
    for (int e = e0 + threadIdx.x; e < e1; e += 256) {
        int d = dst[e];
        int b = d >> SHIFT;
        int p = atomicAdd(&cur[b], 1);
        bin[base[b] + p] = (u32)src[e] | ((u32)(d & (NPBKT - 1)) << 16);
    }
}

__global__ __launch_bounds__(256) void binB_kernel(const u32* __restrict__ bin,
                                                   const int* __restrict__ bbase,
                                                   int* __restrict__ off,
                                                   u16* __restrict__ csr) {
    __shared__ int deg[NPBKT];
    __shared__ int sc[NPBKT];
    __shared__ int cur[NPBKT];
    const int b = blockIdx.x, t = threadIdx.x;
    const int seg0 = bbase[b], seg1 = bbase[b + 1];
    if (t < NPBKT) { deg[t] = 0; cur[t] = 0; }
    __syncthreads();
    for (int i = seg0 + t; i < seg1; i += 256)
        atomicAdd(&deg[(bin[i] >> 16) & (NPBKT - 1)], 1);
    __syncthreads();
    if (t < NPBKT) sc[t] = deg[t];
    __syncthreads();
    for (int d = 1; d < NPBKT; d <<= 1) {
        int v = 0;
        if (t < NPBKT && t >= d) v = sc[t - d];
        __syncthreads();
        if (t < NPBKT) sc[t] += v;
        __syncthreads();
    }
    if (t < NPBKT) {
        sc[t] -= deg[t];
        int node = b * NPBKT + t;
        if (node < NN) off[node] = seg0 + sc[t];
        if (b == 0 && t == 0) off[NN] = NE;
    }
    __syncthreads();
    for (int i = seg0 + t; i < seg1; i += 256) {
        u32 e = bin[i];
        int n = (e >> 16) & (NPBKT - 1);
        int p = atomicAdd(&cur[n], 1);
        csr[seg0 + sc[n] + p] = (u16)(e & 0xFFFF);
    }
}

// ============ weight prep: transpose + split into bf16 hi/lo planes ======
__global__ __launch_bounds__(256) void prep_kernel(const float* __restrict__ W1,
        const float* __restrict__ W2, const float* __restrict__ W3,
        u16* __restrict__ wt) {
    int idx = blockIdx.x * 256 + threadIdx.x;
    if (idx >= 2 * 40960) return;
    int b = idx / 40960, r = idx - b * 40960;
    float v; int hioff, losz;
    if (r < 16384) {
        int col = r >> 7, k = r & 127;
        v = W1[b * 24576 + k * 128 + col];
        hioff = b * 81920 + r; losz = 16384;
    } else if (r < 32768) {
        int rr = r - 16384; int col = rr >> 7, k = rr & 127;
        v = W2[b * 16384 + k * 128 + col];
        hioff = b * 81920 + 32768 + rr; losz = 16384;
    } else {
        int rr = r - 32768; int col = rr >> 7, k = rr & 127;
        v = W3[b * 8192 + k * 64 + col];
        hioff = b * 81920 + 65536 + rr; losz = 8192;
    }
    u16 hi = f2bf(v);
    u16 lo = f2bf(v - bf2f(hi));
    wt[hioff] = hi; wt[hioff + losz] = lo;
}

// ============ grep partials (no atomics) ============
__global__ __launch_bounds__(256) void grep_kernel(const float* __restrict__ h,
                                                   float* __restrict__ partial) {
    const int c  = threadIdx.x & 63;
    const int rl = threadIdx.x >> 6;
    float acc = 0.f;
    for (int r = blockIdx.x * 4 + rl; r < NN; r += gridDim.x * 4)
        acc += h[r * H + c];
    __shared__ float s[4][64];
    s[rl][c] = acc;
    __syncthreads();
    if (threadIdx.x < 64)
        partial[blockIdx.x * 64 + threadIdx.x] =
            s[0][threadIdx.x] + s[1][threadIdx.x] +
            s[2][threadIdx.x] + s[3][threadIdx.x];
}

// ============ b1e: reduce partials + fold grep term into layer-1 bias ====
__global__ __launch_bounds__(256) void b1e_kernel(const float* __restrict__ partial,
        const float* __restrict__ W1, const float* __restrict__ b1,
        float* __restrict__ b1e) {
    __shared__ float sg[4][64];
    __shared__ float g[64];
    const int t = threadIdx.x;
    const int c = t & 63, rl = t >> 6;
    float s = 0.f;
    for (int i = rl; i < 256; i += 4) s += partial[i * 64 + c];
    sg[rl][c] = s;
    __syncthreads();
    if (t < 64) g[t] = sg[0][t] + sg[1][t] + sg[2][t] + sg[3][t];
    __syncthreads();
    if (t < 128) {
        float s2 = b1[t];
        for (int k = 0; k < 64; ++k)
            s2 = fmaf(g[k], W1[(128 + k) * 128 + t], s2);
        b1e[t] = s2;
    }
}

// ============ gather (R5 known-good): 16 lanes x float4, 4 chains ========
__global__ __launch_bounds__(256) void gather_kernel(const float* __restrict__ h,
                                                     const u16* __restrict__ csr,
                                                     const int* __restrict__ off,
                                                     float* __restrict__ agg) {
    const int wid = blockIdx.x * 4 + (threadIdx.x >> 6);
    if (wid >= NN) return;
    const int lane = threadIdx.x & 63;
    const int g = lane >> 4, sub = lane & 15;
    const int beg = off[wid], end = off[wid + 1];
    float4 acc = {0.f, 0.f, 0.f, 0.f};
    for (int e = beg + g; e < end; e += 4) {
        int s = csr[e];
        float4 v = *(const float4*)&h[(size_t)s * H + sub * 4];
        acc.x += v.x; acc.y += v.y; acc.z += v.z; acc.w += v.w;
    }
#pragma unroll
    for (int o = 16; o <= 32; o <<= 1) {
        acc.x += __shfl_xor(acc.x, o);
        acc.y += __shfl_xor(acc.y, o);
        acc.z += __shfl_xor(acc.z, o);
        acc.w += __shfl_xor(acc.w, o);
    }
    if (g == 0)
        *(float4*)&agg[(size_t)wid * H + sub * 4] = acc;
}

// ============ swapped-operand barrier-free MFMA MLP (spill-free) ============
// D = W^T · X^T: node index rides the C-layout column (lane&15). Output tiles
// processed in PAIRS; each pair is converted to the next layer's B-fragment
// immediately (bias+relu+shfl), so no layer-wide register arrays exist.
// LDS: w1hi only (32 KB, swizzled). w2hi/lo planes/w3 stream from L2.
// One 16-node strip per wave; no barriers after the fill.
#define MLP_MFMA(d, a, b) d = __builtin_amdgcn_mfma_f32_16x16x32_bf16(a, b, d, 0, 0, 0)

__global__ __launch_bounds__(256, 3) void mlp_mfma(
    const float* __restrict__ agg, const float* __restrict__ hin,
    const float* __restrict__ b1e, const u16* __restrict__ wt,
    const float* __restrict__ b2, const float* __restrict__ b3,
    float* __restrict__ out)
{
    __shared__ u16 lw[16384];            // w1hi, XOR-swizzled
    const int t = threadIdx.x;
#pragma unroll
    for (int i = t; i < 2048; i += 256) {
        const int col = i >> 4, kb = i & 15;
        s16v8 v = *(const s16v8*)(wt + col * 128 + kb * 8);
        const int slot = (kb & 8) | ((kb ^ col) & 7);
        *(s16v8*)&lw[col * 128 + slot * 8] = v;
    }
    __syncthreads();

    const u16* w1lo = wt + 16384;
    const u16* w2hi = wt + 32768;
    const u16* w2lo = wt + 49152;
    const u16* w3hi = wt + 65536;
    const u16* w3lo = wt + 73728;

    const int lane = t & 63, nd = lane & 15, g = lane >> 4;
    const int s = blockIdx.x * 4 + (t >> 6);
    if (s >= 3125) return;
    const int n0 = s * 16;

    // ---- x B-frags: lane nd holds node n0+nd, k-chunk g*8 per ks ----
    s16v8 xh[4], xl[4];
#pragma unroll
    for (int ks = 0; ks < 4; ++ks) {
        const float* sp = ((ks < 2) ? agg : hin) +
                          (size_t)(n0 + nd) * 64 + (ks & 1) * 32 + g * 8;
        float4 u0 = *(const float4*)sp;
        float4 u1 = *(const float4*)(sp + 4);
        float f[8] = {u0.x, u0.y, u0.z, u0.w, u1.x, u1.y, u1.z, u1.w};
#pragma unroll
        for (int j = 0; j < 8; ++j) {
            u16 hb = f2bf(f[j]);
            xh[ks][j] = (short)hb;
            xl[ks][j] = (short)f2bf(f[j] - bf2f(hb));
        }
    }

    // ---- L1: pairs of col-tiles -> y B-frags directly ----
    s16v8 yh[4], yl[4];
#pragma unroll
    for (int kp = 0; kp < 4; ++kp) {
        const int col0 = (kp * 2) * 16 + nd;
        const int col1 = (kp * 2 + 1) * 16 + nd;
        f32v4 a0 = {0.f, 0.f, 0.f, 0.f}, a1 = {0.f, 0.f, 0.f, 0.f};
#pragma unroll
        for (int ks = 0; ks < 4; ++ks) {
            const int kb = ks * 4 + g;
            const int sl0 = (kb & 8) | ((kb ^ col0) & 7);
            s16v8 Ah0 = *(const s16v8*)&lw[col0 * 128 + sl0 * 8];
            s16v8 Al0 = *(const s16v8*)(w1lo + col0 * 128 + kb * 8);
            MLP_MFMA(a0, Ah0, xh[ks]);
            MLP_MFMA(a0, Ah0, xl[ks]);
            MLP_MFMA(a0, Al0, xh[ks]);
            const int sl1 = (kb & 8) | ((kb ^ col1) & 7);
            s16v8 Ah1 = *(const s16v8*)&lw[col1 * 128 + sl1 * 8];
            s16v8 Al1 = *(const s16v8*)(w1lo + col1 * 128 + kb * 8);
            MLP_MFMA(a1, Ah1, xh[ks]);
            MLP_MFMA(a1, Ah1, xl[ks]);
            MLP_MFMA(a1, Al1, xh[ks]);
        }
        float4 bb0 = *(const float4*)&b1e[(kp * 2) * 16 + g * 4];
        float4 bb1 = *(const float4*)&b1e[(kp * 2 + 1) * 16 + g * 4];
        float h0[4] = {fmaxf(a0[0] + bb0.x, 0.f), fmaxf(a0[1] + bb0.y, 0.f),
                       fmaxf(a0[2] + bb0.z, 0.f), fmaxf(a0[3] + bb0.w, 0.f)};
        float h1v[4] = {fmaxf(a1[0] + bb1.x, 0.f), fmaxf(a1[1] + bb1.y, 0.f),
                        fmaxf(a1[2] + bb1.z, 0.f), fmaxf(a1[3] + bb1.w, 0.f)};
        float f[8];
#pragma unroll
        for (int jh = 0; jh < 2; ++jh) {
            const int srcl = nd + 16 * ((g * 2 + jh) & 3);
#pragma unroll
            for (int js = 0; js < 4; ++js) {
                float v0 = __shfl(h0[js], srcl);
                float v1 = __shfl(h1v[js], srcl);
                f[jh * 4 + js] = (g >> 1) ? v1 : v0;
            }
        }
#pragma unroll
        for (int j = 0; j < 8; ++j) {
            u16 hb = f2bf(f[j]);
            yh[kp][j] = (short)hb;
            yl[kp][j] = (short)f2bf(f[j] - bf2f(hb));
        }
    }

    // ---- L2: same pattern, w2hi streamed from L2 ----
    s16v8 zh[4], zl[4];
#pragma unroll
    for (int kp = 0; kp < 4; ++kp) {
        const int col0 = (kp * 2) * 16 + nd;
        const int col1 = (kp * 2 + 1) * 16 + nd;
        f32v4 a0 = {0.f, 0.f, 0.f, 0.f}, a1 = {0.f, 0.f, 0.f, 0.f};
#pragma unroll
        for (int ks = 0; ks < 4; ++ks) {
            const int kb = ks * 4 + g;
            s16v8 Ah0 = *(const s16v8*)(w2hi + col0 * 128 + kb * 8);
            s16v8 Al0 = *(const s16v8*)(w2lo + col0 * 128 + kb * 8);
            MLP_MFMA(a0, Ah0, yh[ks]);
            MLP_MFMA(a0, Ah0, yl[ks]);
            MLP_MFMA(a0, Al0, yh[ks]);
            s16v8 Ah1 = *(const s16v8*)(w2hi + col1 * 128 + kb * 8);
            s16v8 Al1 = *(const s16v8*)(w2lo + col1 * 128 + kb * 8);
            MLP_MFMA(a1, Ah1, yh[ks]);
            MLP_MFMA(a1, Ah1, yl[ks]);
            MLP_MFMA(a1, Al1, yh[ks]);
        }
        float4 bb0 = *(const float4*)&b2[(kp * 2) * 16 + g * 4];
        float4 bb1 = *(const float4*)&b2[(kp * 2 + 1) * 16 + g * 4];
        float h0[4] = {fmaxf(a0[0] + bb0.x, 0.f), fmaxf(a0[1] + bb0.y, 0.f),
                       fmaxf(a0[2] + bb0.z, 0.f), fmaxf(a0[3] + bb0.w, 0.f)};
        float h1v[4] = {fmaxf(a1[0] + bb1.x, 0.f), fmaxf(a1[1] + bb1.y, 0.f),
                        fmaxf(a1[2] + bb1.z, 0.f), fmaxf(a1[3] + bb1.w, 0.f)};
        float f[8];
#pragma unroll
        for (int jh = 0; jh < 2; ++jh) {
            const int srcl = nd + 16 * ((g * 2 + jh) & 3);
#pragma unroll
            for (int js = 0; js < 4; ++js) {
                float v0 = __shfl(h0[js], srcl);
                float v1 = __shfl(h1v[js], srcl);
                f[jh * 4 + js] = (g >> 1) ? v1 : v0;
            }
        }
#pragma unroll
        for (int j = 0; j < 8; ++j) {
            u16 hb = f2bf(f[j]);
            zh[kp][j] = (short)hb;
            zl[kp][j] = (short)f2bf(f[j] - bf2f(hb));
        }
    }

    // ---- L3 (streamed) + row L2 norm + store ----
    float v[4][4];
    float ss = 0.f;
#pragma unroll
    for (int ct = 0; ct < 4; ++ct) {
        const int col = ct * 16 + nd;
        f32v4 a3 = {0.f, 0.f, 0.f, 0.f};
#pragma unroll
        for (int ks = 0; ks < 4; ++ks) {
            const int kb = ks * 4 + g;
            s16v8 Ah = *(const s16v8*)(w3hi + col * 128 + kb * 8);
            s16v8 Al = *(const s16v8*)(w3lo + col * 128 + kb * 8);
            MLP_MFMA(a3, Ah, zh[ks]);
            MLP_MFMA(a3, Ah, zl[ks]);
            MLP_MFMA(a3, Al, zh[ks]);
        }
        float4 bb = *(const float4*)&b3[ct * 16 + g * 4];
        v[ct][0] = a3[0] + bb.x;
        v[ct][1] = a3[1] + bb.y;
        v[ct][2] = a3[2] + bb.z;
        v[ct][3] = a3[3] + bb.w;
#pragma unroll
        for (int j = 0; j < 4; ++j) ss = fmaf(v[ct][j], v[ct][j], ss);
    }
    ss += __shfl_xor(ss, 16);
    ss += __shfl_xor(ss, 32);
    const float inv = rsqrtf(ss);
    float* op = out + (size_t)(n0 + nd) * 64 + g * 4;
#pragma unroll
    for (int ct = 0; ct < 4; ++ct)
#pragma unroll
        for (int j = 0; j < 4; ++j)
            op[ct * 16 + j] = v[ct][j] * inv;
}

// -------------------------------------------------------------------------
extern "C" void kernel_launch(void* const* d_in, const int* in_sizes, int n_in,
                              void* d_out, int out_size, void* d_ws, size_t ws_size,
                              hipStream_t stream) {
    const float* hidden = (const float*)d_in[0];
    const int*   src    = (const int*)d_in[1];
    const int*   dst    = (const int*)d_in[2];
    const float* W1f    = (const float*)d_in[3];
    const float* b1f    = (const float*)d_in[4];
    const float* W2f    = (const float*)d_in[5];
    const float* b2f    = (const float*)d_in[6];
    const float* W3f    = (const float*)d_in[7];
    const float* b3f    = (const float*)d_in[8];

    float* agg     = (float*)d_ws;                        // NN*H
    float* b1e     = agg + (size_t)NN * H;                // 128
    float* partial = b1e + 128;                           // 256*64
    float* hA      = partial + 256 * 64;                  // NN*H
    int*   bbase   = (int*)(hA + (size_t)NN * H);         // NB+1
    int*   off     = bbase + (NB + 1);                    // NN+1
    int*   chist   = off + (NN + 1);                      // NCH*NB
    u32*   bin     = (u32*)(chist + NCH * NB);            // NE
    u16*   csr     = (u16*)(bin + NE);                    // NE
    u16*   wt      = (u16*)(((uintptr_t)(csr + NE) + 255) & ~(uintptr_t)255);

    // ---- one-time per call: bucketized CSR + weight planes ----
    hist_kernel<<<NCH, 256, 0, stream>>>(dst, chist);
    cscan_kernel<<<1, 512, 0, stream>>>(chist, bbase);
    scat_kernel<<<NCH, 256, 0, stream>>>(src, dst, chist, bin);
    binB_kernel<<<NB, 256, 0, stream>>>(bin, bbase, off, csr);
    prep_kernel<<<(2 * 40960 + 255) / 256, 256, 0, stream>>>(W1f, W2f, W3f, wt);

    const float* hin = hidden;
    float* houts[4] = { hA, (float*)d_out, hA, (float*)d_out };

    for (int it = 0; it < 4; ++it) {
        const int blk = it >> 1;
        grep_kernel<<<256, 256, 0, stream>>>(hin, partial);
        b1e_kernel<<<1, 256, 0, stream>>>(partial, W1f + blk * 24576, b1f + blk * 128, b1e);
        gather_kernel<<<(NN + 3) / 4, 256, 0, stream>>>(hin, csr, off, agg);
        mlp_mfma<<<782, 256, 0, stream>>>(agg, hin, b1e, wt + blk * 81920,
            b2f + blk * 128, b3f + blk * 64, houts[it]);
        hin = houts[it];
    }
}

// Round 9
// 553.503 us; speedup vs baseline: 2.3811x; 1.2359x over previous
//
#include <hip/hip_runtime.h>
#include <math.h>

#define NN 50000
#define NE 1600000
#define H  64

#define SHIFT 7                 // 128 nodes per bucket
#define NPBKT 128
#define NB    391               // ceil(50000/128)
#define CHUNK 4096
#define NCH   391               // ceil(NE/CHUNK)

typedef __attribute__((ext_vector_type(8))) short s16v8;   // 8 bf16
typedef __attribute__((ext_vector_type(4))) float f32v4;   // MFMA acc
typedef unsigned short u16;
typedef unsigned int   u32;

__device__ __forceinline__ u16 f2bf(float x) {             // RNE f32->bf16
    union { float f; unsigned u; } v; v.f = x;
    unsigned r = v.u + 0x7FFF + ((v.u >> 16) & 1);
    return (u16)(r >> 16);
}
__device__ __forceinline__ float bf2f(u16 h) {
    union { float f; unsigned u; } v; v.u = ((unsigned)h) << 16; return v.f;
}

// ============ CSR build, bucketized ============
__global__ __launch_bounds__(256) void hist_kernel(const int* __restrict__ dst,
                                                   int* __restrict__ chunkhist) {
    __shared__ int h[NB];
    const int c = blockIdx.x;
    for (int b = threadIdx.x; b < NB; b += 256) h[b] = 0;
    __syncthreads();
    const int e0 = c * CHUNK, e1 = min(NE, e0 + CHUNK);
    for (int e = e0 + threadIdx.x; e < e1; e += 256)
        atomicAdd(&h[dst[e] >> SHIFT], 1);
    __syncthreads();
    for (int b = threadIdx.x; b < NB; b += 256)
        chunkhist[c * NB + b] = h[b];
}

__global__ __launch_bounds__(512) void cscan_kernel(int* __restrict__ chunkhist,
                                                    int* __restrict__ bbase) {
    __shared__ int s[512];
    const int t = threadIdx.x;
    int tot = 0;
    if (t < NB)
        for (int c = 0; c < NCH; ++c) tot += chunkhist[c * NB + t];
    s[t] = (t < NB) ? tot : 0;
    __syncthreads();
    for (int d = 1; d < 512; d <<= 1) {
        int v = (t >= d) ? s[t - d] : 0;
        __syncthreads();
        s[t] += v;
        __syncthreads();
    }
    if (t < NB) {
        int base = s[t] - tot;             // exclusive
        bbase[t] = base;
        if (t == NB - 1) bbase[NB] = s[t];
        int run = base;
        for (int c = 0; c < NCH; ++c) {
            int tmp = chunkhist[c * NB + t];
            chunkhist[c * NB + t] = run;
            run += tmp;
        }
    }
}

__global__ __launch_bounds__(256) void scat_kernel(const int* __restrict__ src,
                                                   const int* __restrict__ dst,
                                                   const int* __restrict__ chunkhist,
                                                   u32* __restrict__ bin) {
    __shared__ int base[NB];
    __shared__ int cur[NB];
    const int c = blockIdx.x;
    for (int b = threadIdx.x; b < NB; b += 256) {
        base[b] = chunkhist[c * NB + b];
        cur[b] = 0;
    }
    __syncthreads();
    const int e0 = c * CHUNK, e1 = min(NE, e0 + CHUNK);
    for (int e = e0 + threadIdx.x; e < e1; e += 256) {
        int d = dst[e];
        int b = d >> SHIFT;
        int p = atomicAdd(&cur[b], 1);
        bin[base[b] + p] = (u32)src[e] | ((u32)(d & (NPBKT - 1)) << 16);
    }
}

__global__ __launch_bounds__(256) void binB_kernel(const u32* __restrict__ bin,
                                                   const int* __restrict__ bbase,
                                                   int* __restrict__ off,
                                                   u16* __restrict__ csr) {
    __shared__ int deg[NPBKT];
    __shared__ int sc[NPBKT];
    __shared__ int cur[NPBKT];
    const int b = blockIdx.x, t = threadIdx.x;
    const int seg0 = bbase[b], seg1 = bbase[b + 1];
    if (t < NPBKT) { deg[t] = 0; cur[t] = 0; }
    __syncthreads();
    for (int i = seg0 + t; i < seg1; i += 256)
        atomicAdd(&deg[(bin[i] >> 16) & (NPBKT - 1)], 1);
    __syncthreads();
    if (t < NPBKT) sc[t] = deg[t];
    __syncthreads();
    for (int d = 1; d < NPBKT; d <<= 1) {
        int v = 0;
        if (t < NPBKT && t >= d) v = sc[t - d];
        __syncthreads();
        if (t < NPBKT) sc[t] += v;
        __syncthreads();
    }
    if (t < NPBKT) {
        sc[t] -= deg[t];
        int node = b * NPBKT + t;
        if (node < NN) off[node] = seg0 + sc[t];
        if (b == 0 && t == 0) off[NN] = NE;
    }
    __syncthreads();
    for (int i = seg0 + t; i < seg1; i += 256) {
        u32 e = bin[i];
        int n = (e >> 16) & (NPBKT - 1);
        int p = atomicAdd(&cur[n], 1);
        csr[seg0 + sc[n] + p] = (u16)(e & 0xFFFF);
    }
}

// ============ weight prep: transpose + split into bf16 hi/lo planes ======
__global__ __launch_bounds__(256) void prep_kernel(const float* __restrict__ W1,
        const float* __restrict__ W2, const float* __restrict__ W3,
        u16* __restrict__ wt) {
    int idx = blockIdx.x * 256 + threadIdx.x;
    if (idx >= 2 * 40960) return;
    int b = idx / 40960, r = idx - b * 40960;
    float v; int hioff, losz;
    if (r < 16384) {
        int col = r >> 7, k = r & 127;
        v = W1[b * 24576 + k * 128 + col];
        hioff = b * 81920 + r; losz = 16384;
    } else if (r < 32768) {
        int rr = r - 16384; int col = rr >> 7, k = rr & 127;
        v = W2[b * 16384 + k * 128 + col];
        hioff = b * 81920 + 32768 + rr; losz = 16384;
    } else {
        int rr = r - 32768; int col = rr >> 7, k = rr & 127;
        v = W3[b * 8192 + k * 64 + col];
        hioff = b * 81920 + 65536 + rr; losz = 8192;
    }
    u16 hi = f2bf(v);
    u16 lo = f2bf(v - bf2f(hi));
    wt[hioff] = hi; wt[hioff + losz] = lo;
}

// ============ grep partials (no atomics) ============
__global__ __launch_bounds__(256) void grep_kernel(const float* __restrict__ h,
                                                   float* __restrict__ partial) {
    const int c  = threadIdx.x & 63;
    const int rl = threadIdx.x >> 6;
    float acc = 0.f;
    for (int r = blockIdx.x * 4 + rl; r < NN; r += gridDim.x * 4)
        acc += h[r * H + c];
    __shared__ float s[4][64];
    s[rl][c] = acc;
    __syncthreads();
    if (threadIdx.x < 64)
        partial[blockIdx.x * 64 + threadIdx.x] =
            s[0][threadIdx.x] + s[1][threadIdx.x] +
            s[2][threadIdx.x] + s[3][threadIdx.x];
}

// ============ b1e: reduce partials + fold grep term into layer-1 bias ====
__global__ __launch_bounds__(256) void b1e_kernel(const float* __restrict__ partial,
        const float* __restrict__ W1, const float* __restrict__ b1,
        float* __restrict__ b1e) {
    __shared__ float sg[4][64];
    __shared__ float g[64];
    const int t = threadIdx.x;
    const int c = t & 63, rl = t >> 6;
    float s = 0.f;
    for (int i = rl; i < 256; i += 4) s += partial[i * 64 + c];
    sg[rl][c] = s;
    __syncthreads();
    if (t < 64) g[t] = sg[0][t] + sg[1][t] + sg[2][t] + sg[3][t];
    __syncthreads();
    if (t < 128) {
        float s2 = b1[t];
        for (int k = 0; k < 64; ++k)
            s2 = fmaf(g[k], W1[(128 + k) * 128 + t], s2);
        b1e[t] = s2;
    }
}

// ============ gather (R5 known-good): 16 lanes x float4, 4 chains ========
__global__ __launch_bounds__(256) void gather_kernel(const float* __restrict__ h,
                                                     const u16* __restrict__ csr,
                                                     const int* __restrict__ off,
                                                     float* __restrict__ agg) {
    const int wid = blockIdx.x * 4 + (threadIdx.x >> 6);
    if (wid >= NN) return;
    const int lane = threadIdx.x & 63;
    const int g = lane >> 4, sub = lane & 15;
    const int beg = off[wid], end = off[wid + 1];
    float4 acc = {0.f, 0.f, 0.f, 0.f};
    for (int e = beg + g; e < end; e += 4) {
        int s = csr[e];
        float4 v = *(const float4*)&h[(size_t)s * H + sub * 4];
        acc.x += v.x; acc.y += v.y; acc.z += v.z; acc.w += v.w;
    }
#pragma unroll
    for (int o = 16; o <= 32; o <<= 1) {
        acc.x += __shfl_xor(acc.x, o);
        acc.y += __shfl_xor(acc.y, o);
        acc.z += __shfl_xor(acc.z, o);
        acc.w += __shfl_xor(acc.w, o);
    }
    if (g == 0)
        *(float4*)&agg[(size_t)wid * H + sub * 4] = acc;
}

// ============ MFMA MLP: 8 waves/block, per-wave col-tile, B hoisted =======
// 64 nodes/block. Wave wl owns output col-tile wl (L1/L2: 8 tiles; L3: waves
// 0-3 own the 4 tiles). B-frags loaded once per layer (8 x b128 from L2,
// shared across all blocks); A-frags stream from one swizzled 32KB hi/lo LDS
// plane; epilogue writes next layer's activations back to the same plane.
#define MLP_MFMA(d, a, b) d = __builtin_amdgcn_mfma_f32_16x16x32_bf16(a, b, d, 0, 0, 0)

__global__ __launch_bounds__(512, 4) void mlp_mfma(
    const float* __restrict__ agg, const float* __restrict__ hin,
    const float* __restrict__ b1e, const u16* __restrict__ wt,
    const float* __restrict__ b2, const float* __restrict__ b3,
    float* __restrict__ out)
{
    __shared__ u16 hhi[64 * 128], hlo[64 * 128];
    __shared__ float ssw[4 * 64];
    const int t = threadIdx.x;
    const int wl = t >> 6, lane = t & 63;
    const int li = lane & 15, g = lane >> 4;
    const int n0 = blockIdx.x * 64;

    const u16* w1hi = wt;
    const u16* w1lo = wt + 16384;
    const u16* w2hi = wt + 32768;
    const u16* w2lo = wt + 49152;
    const u16* w3hi = wt + 65536;
    const u16* w3lo = wt + 73728;

    // ---- stage x = [agg | hidden]: thread t -> row t>>3, 16 cols ----
    {
        const int row = t >> 3, col0 = (t & 7) * 16;
        const int node = min(n0 + row, NN - 1);
        const float* sp = (col0 < 64) ? (agg + (size_t)node * 64 + col0)
                                      : (hin + (size_t)node * 64 + (col0 - 64));
        float4 u0 = *(const float4*)sp;
        float4 u1 = *(const float4*)(sp + 4);
        float4 u2 = *(const float4*)(sp + 8);
        float4 u3 = *(const float4*)(sp + 12);
        float f[16] = {u0.x, u0.y, u0.z, u0.w, u1.x, u1.y, u1.z, u1.w,
                       u2.x, u2.y, u2.z, u2.w, u3.x, u3.y, u3.z, u3.w};
        s16v8 hv0, lv0, hv1, lv1;
#pragma unroll
        for (int j = 0; j < 8; ++j) {
            u16 hb = f2bf(f[j]);
            hv0[j] = (short)hb;
            lv0[j] = (short)f2bf(f[j] - bf2f(hb));
            u16 hb1 = f2bf(f[8 + j]);
            hv1[j] = (short)hb1;
            lv1[j] = (short)f2bf(f[8 + j] - bf2f(hb1));
        }
        const int cb = col0 >> 3;
        const int a0 = row * 128 + (((cb ^ (row & 7)) << 3));
        const int a1 = row * 128 + ((((cb + 1) ^ (row & 7)) << 3));
        *(s16v8*)&hhi[a0] = hv0; *(s16v8*)&hlo[a0] = lv0;
        *(s16v8*)&hhi[a1] = hv1; *(s16v8*)&hlo[a1] = lv1;
    }
    __syncthreads();

    // ================= L1 (x -> h1) =================
    {
        const int col = wl * 16 + li;
        s16v8 Bh[4], Bl[4];
#pragma unroll
        for (int ks = 0; ks < 4; ++ks) {
            Bh[ks] = *(const s16v8*)(w1hi + col * 128 + ks * 32 + g * 8);
            Bl[ks] = *(const s16v8*)(w1lo + col * 128 + ks * 32 + g * 8);
        }
        f32v4 acc[4];
#pragma unroll
        for (int i = 0; i < 4; ++i) acc[i] = (f32v4){0.f, 0.f, 0.f, 0.f};
#pragma unroll
        for (int rt = 0; rt < 4; ++rt) {
            const int row = rt * 16 + li;
#pragma unroll
            for (int ks = 0; ks < 4; ++ks) {
                const int kb = ks * 4 + g;
                const int addr = row * 128 + ((kb ^ (row & 7)) << 3);
                s16v8 Ah = *(const s16v8*)&hhi[addr];
                s16v8 Al = *(const s16v8*)&hlo[addr];
                MLP_MFMA(acc[rt], Ah, Bh[ks]);
                MLP_MFMA(acc[rt], Ah, Bl[ks]);
                MLP_MFMA(acc[rt], Al, Bh[ks]);
            }
        }
        __syncthreads();                        // all x reads complete
        const float bb = b1e[col];
        const int cb = col >> 3, c7 = col & 7;
#pragma unroll
        for (int rt = 0; rt < 4; ++rt) {
#pragma unroll
            for (int r = 0; r < 4; ++r) {
                float hv = fmaxf(acc[rt][r] + bb, 0.f);
                u16 hb = f2bf(hv);
                u16 lb = f2bf(hv - bf2f(hb));
                const int row = rt * 16 + g * 4 + r;
                const int addr = row * 128 + (((cb ^ (row & 7)) << 3) | c7);
                hhi[addr] = hb; hlo[addr] = lb;
            }
        }
    }
    __syncthreads();

    // ================= L2 (h1 -> h2) =================
    {
        const int col = wl * 16 + li;
        s16v8 Bh[4], Bl[4];
#pragma unroll
        for (int ks = 0; ks < 4; ++ks) {
            Bh[ks] = *(const s16v8*)(w2hi + col * 128 + ks * 32 + g * 8);
            Bl[ks] = *(const s16v8*)(w2lo + col * 128 + ks * 32 + g * 8);
        }
        f32v4 acc[4];
#pragma unroll
        for (int i = 0; i < 4; ++i) acc[i] = (f32v4){0.f, 0.f, 0.f, 0.f};
#pragma unroll
        for (int rt = 0; rt < 4; ++rt) {
            const int row = rt * 16 + li;
#pragma unroll
            for (int ks = 0; ks < 4; ++ks) {
                const int kb = ks * 4 + g;
                const int addr = row * 128 + ((kb ^ (row & 7)) << 3);
                s16v8 Ah = *(const s16v8*)&hhi[addr];
                s16v8 Al = *(const s16v8*)&hlo[addr];
                MLP_MFMA(acc[rt], Ah, Bh[ks]);
                MLP_MFMA(acc[rt], Ah, Bl[ks]);
                MLP_MFMA(acc[rt], Al, Bh[ks]);
            }
        }
        __syncthreads();
        const float bb = b2[col];
        const int cb = col >> 3, c7 = col & 7;
#pragma unroll
        for (int rt = 0; rt < 4; ++rt) {
#pragma unroll
            for (int r = 0; r < 4; ++r) {
                float hv = fmaxf(acc[rt][r] + bb, 0.f);
                u16 hb = f2bf(hv);
                u16 lb = f2bf(hv - bf2f(hb));
                const int row = rt * 16 + g * 4 + r;
                const int addr = row * 128 + (((cb ^ (row & 7)) << 3) | c7);
                hhi[addr] = hb; hlo[addr] = lb;
            }
        }
    }
    __syncthreads();

    // ================= L3 (h2 -> out, waves 0-3) + row L2 norm ============
    float v[4][4];
    if (wl < 4) {
        const int col = wl * 16 + li;
        s16v8 Bh[4], Bl[4];
#pragma unroll
        for (int ks = 0; ks < 4; ++ks) {
            Bh[ks] = *(const s16v8*)(w3hi + col * 128 + ks * 32 + g * 8);
            Bl[ks] = *(const s16v8*)(w3lo + col * 128 + ks * 32 + g * 8);
        }
        f32v4 acc[4];
#pragma unroll
        for (int i = 0; i < 4; ++i) acc[i] = (f32v4){0.f, 0.f, 0.f, 0.f};
#pragma unroll
        for (int rt = 0; rt < 4; ++rt) {
            const int row = rt * 16 + li;
#pragma unroll
            for (int ks = 0; ks < 4; ++ks) {
                const int kb = ks * 4 + g;
                const int addr = row * 128 + ((kb ^ (row & 7)) << 3);
                s16v8 Ah = *(const s16v8*)&hhi[addr];
                s16v8 Al = *(const s16v8*)&hlo[addr];
                MLP_MFMA(acc[rt], Ah, Bh[ks]);
                MLP_MFMA(acc[rt], Ah, Bl[ks]);
                MLP_MFMA(acc[rt], Al, Bh[ks]);
            }
        }
        const float bb = b3[col];
#pragma unroll
        for (int rt = 0; rt < 4; ++rt) {
#pragma unroll
            for (int r = 0; r < 4; ++r) {
                float vv = acc[rt][r] + bb;
                v[rt][r] = vv;
                float s2 = vv * vv;
#pragma unroll
                for (int o = 1; o <= 8; o <<= 1) s2 += __shfl_xor(s2, o);
                if (li == 0) ssw[wl * 64 + rt * 16 + g * 4 + r] = s2;
            }
        }
    }
    __syncthreads();
    if (wl < 4) {
        const int col = wl * 16 + li;
#pragma unroll
        for (int rt = 0; rt < 4; ++rt) {
#pragma unroll
            for (int r = 0; r < 4; ++r) {
                const int row = rt * 16 + g * 4 + r;
                const float tot = ssw[row] + ssw[64 + row] +
                                  ssw[128 + row] + ssw[192 + row];
                const float inv = rsqrtf(tot);
                const int node = n0 + row;
                if (node < NN)
                    out[(size_t)node * 64 + col] = v[rt][r] * inv;
            }
        }
    }
}

// -------------------------------------------------------------------------
extern "C" void kernel_launch(void* const* d_in, const int* in_sizes, int n_in,
                              void* d_out, int out_size, void* d_ws, size_t ws_size,
                              hipStream_t stream) {
    const float* hidden = (const float*)d_in[0];
    const int*   src    = (const int*)d_in[1];
    const int*   dst    = (const int*)d_in[2];
    const float* W1f    = (const float*)d_in[3];
    const float* b1f    = (const float*)d_in[4];
    const float* W2f    = (const float*)d_in[5];
    const float* b2f    = (const float*)d_in[6];
    const float* W3f    = (const float*)d_in[7];
    const float* b3f    = (const float*)d_in[8];

    float* agg     = (float*)d_ws;                        // NN*H
    float* b1e     = agg + (size_t)NN * H;                // 128
    float* partial = b1e + 128;                           // 256*64
    float* hA      = partial + 256 * 64;                  // NN*H
    int*   bbase   = (int*)(hA + (size_t)NN * H);         // NB+1
    int*   off     = bbase + (NB + 1);                    // NN+1
    int*   chist   = off + (NN + 1);                      // NCH*NB
    u32*   bin     = (u32*)(chist + NCH * NB);            // NE
    u16*   csr     = (u16*)(bin + NE);                    // NE
    u16*   wt      = (u16*)(((uintptr_t)(csr + NE) + 255) & ~(uintptr_t)255);

    // ---- one-time per call: bucketized CSR + weight planes ----
    hist_kernel<<<NCH, 256, 0, stream>>>(dst, chist);
    cscan_kernel<<<1, 512, 0, stream>>>(chist, bbase);
    scat_kernel<<<NCH, 256, 0, stream>>>(src, dst, chist, bin);
    binB_kernel<<<NB, 256, 0, stream>>>(bin, bbase, off, csr);
    prep_kernel<<<(2 * 40960 + 255) / 256, 256, 0, stream>>>(W1f, W2f, W3f, wt);

    const float* hin = hidden;
    float* houts[4] = { hA, (float*)d_out, hA, (float*)d_out };

    for (int it = 0; it < 4; ++it) {
        const int blk = it >> 1;
        grep_kernel<<<256, 256, 0, stream>>>(hin, partial);
        b1e_kernel<<<1, 256, 0, stream>>>(partial, W1f + blk * 24576, b1f + blk * 128, b1e);
        gather_kernel<<<(NN + 3) / 4, 256, 0, stream>>>(hin, csr, off, agg);
        mlp_mfma<<<(NN + 63) / 64, 512, 0, stream>>>(agg, hin, b1e, wt + blk * 81920,
            b2f + blk * 128, b3f + blk * 64, houts[it]);
        hin = houts[it];
    }
}

// Round 10
// 477.108 us; speedup vs baseline: 2.7624x; 1.1601x over previous
//
#include <hip/hip_runtime.h>
#include <math.h>

#define NN 50000
#define NE 1600000
#define H  64

#define SHIFT 7                 // 128 nodes per bucket
#define NPBKT 128
#define NB    391               // ceil(50000/128)
#define CHUNK 4096
#define NCH   391               // ceil(NE/CHUNK)

typedef __attribute__((ext_vector_type(8))) short s16v8;   // 8 bf16
typedef __attribute__((ext_vector_type(4))) float f32v4;   // MFMA acc
typedef __attribute__((ext_vector_type(8))) _Float16 f16v8;
typedef unsigned short u16;
typedef unsigned int   u32;

__device__ __forceinline__ u16 f2bf(float x) {             // RNE f32->bf16
    union { float f; unsigned u; } v; v.f = x;
    unsigned r = v.u + 0x7FFF + ((v.u >> 16) & 1);
    return (u16)(r >> 16);
}
__device__ __forceinline__ float bf2f(u16 h) {
    union { float f; unsigned u; } v; v.u = ((unsigned)h) << 16; return v.f;
}

// ============ CSR build, bucketized ============
__global__ __launch_bounds__(256) void hist_kernel(const int* __restrict__ dst,
                                                   int* __restrict__ chunkhist) {
    __shared__ int h[NB];
    const int c = blockIdx.x;
    for (int b = threadIdx.x; b < NB; b += 256) h[b] = 0;
    __syncthreads();
    const int e0 = c * CHUNK, e1 = min(NE, e0 + CHUNK);
    for (int e = e0 + threadIdx.x; e < e1; e += 256)
        atomicAdd(&h[dst[e] >> SHIFT], 1);
    __syncthreads();
    for (int b = threadIdx.x; b < NB; b += 256)
        chunkhist[c * NB + b] = h[b];
}

__global__ __launch_bounds__(512) void cscan_kernel(int* __restrict__ chunkhist,
                                                    int* __restrict__ bbase) {
    __shared__ int s[512];
    const int t = threadIdx.x;
    int tot = 0;
    if (t < NB)
        for (int c = 0; c < NCH; ++c) tot += chunkhist[c * NB + t];
    s[t] = (t < NB) ? tot : 0;
    __syncthreads();
    for (int d = 1; d < 512; d <<= 1) {
        int v = (t >= d) ? s[t - d] : 0;
        __syncthreads();
        s[t] += v;
        __syncthreads();
    }
    if (t < NB) {
        int base = s[t] - tot;             // exclusive
        bbase[t] = base;
        if (t == NB - 1) bbase[NB] = s[t];
        int run = base;
        for (int c = 0; c < NCH; ++c) {
            int tmp = chunkhist[c * NB + t];
            chunkhist[c * NB + t] = run;
            run += tmp;
        }
    }
}

__global__ __launch_bounds__(256) void scat_kernel(const int* __restrict__ src,
                                                   const int* __restrict__ dst,
                                                   const int* __restrict__ chunkhist,
                                                   u32* __restrict__ bin) {
    __shared__ int base[NB];
    __shared__ int cur[NB];
    const int c = blockIdx.x;
    for (int b = threadIdx.x; b < NB; b += 256) {
        base[b] = chunkhist[c * NB + b];
        cur[b] = 0;
    }
    __syncthreads();
    const int e0 = c * CHUNK, e1 = min(NE, e0 + CHUNK);
    for (int e = e0 + threadIdx.x; e < e1; e += 256) {
        int d = dst[e];
        int b = d >> SHIFT;
        int p = atomicAdd(&cur[b], 1);
        bin[base[b] + p] = (u32)src[e] | ((u32)(d & (NPBKT - 1)) << 16);
    }
}

__global__ __launch_bounds__(256) void binB_kernel(const u32* __restrict__ bin,
                                                   const int* __restrict__ bbase,
                                                   int* __restrict__ off,
                                                   u16* __restrict__ csr) {
    __shared__ int deg[NPBKT];
    __shared__ int sc[NPBKT];
    __shared__ int cur[NPBKT];
    const int b = blockIdx.x, t = threadIdx.x;
    const int seg0 = bbase[b], seg1 = bbase[b + 1];
    if (t < NPBKT) { deg[t] = 0; cur[t] = 0; }
    __syncthreads();
    for (int i = seg0 + t; i < seg1; i += 256)
        atomicAdd(&deg[(bin[i] >> 16) & (NPBKT - 1)], 1);
    __syncthreads();
    if (t < NPBKT) sc[t] = deg[t];
    __syncthreads();
    for (int d = 1; d < NPBKT; d <<= 1) {
        int v = 0;
        if (t < NPBKT && t >= d) v = sc[t - d];
        __syncthreads();
        if (t < NPBKT) sc[t] += v;
        __syncthreads();
    }
    if (t < NPBKT) {
        sc[t] -= deg[t];
        int node = b * NPBKT + t;
        if (node < NN) off[node] = seg0 + sc[t];
        if (b == 0 && t == 0) off[NN] = NE;
    }
    __syncthreads();
    for (int i = seg0 + t; i < seg1; i += 256) {
        u32 e = bin[i];
        int n = (e >> 16) & (NPBKT - 1);
        int p = atomicAdd(&cur[n], 1);
        csr[seg0 + sc[n] + p] = (u16)(e & 0xFFFF);
    }
}

// ============ weight prep: transpose + split into bf16 hi/lo planes ======
__global__ __launch_bounds__(256) void prep_kernel(const float* __restrict__ W1,
        const float* __restrict__ W2, const float* __restrict__ W3,
        u16* __restrict__ wt) {
    int idx = blockIdx.x * 256 + threadIdx.x;
    if (idx >= 2 * 40960) return;
    int b = idx / 40960, r = idx - b * 40960;
    float v; int hioff, losz;
    if (r < 16384) {
        int col = r >> 7, k = r & 127;
        v = W1[b * 24576 + k * 128 + col];
        hioff = b * 81920 + r; losz = 16384;
    } else if (r < 32768) {
        int rr = r - 16384; int col = rr >> 7, k = rr & 127;
        v = W2[b * 16384 + k * 128 + col];
        hioff = b * 81920 + 32768 + rr; losz = 16384;
    } else {
        int rr = r - 32768; int col = rr >> 7, k = rr & 127;
        v = W3[b * 8192 + k * 64 + col];
        hioff = b * 81920 + 65536 + rr; losz = 8192;
    }
    u16 hi = f2bf(v);
    u16 lo = f2bf(v - bf2f(hi));
    wt[hioff] = hi; wt[hioff + losz] = lo;
}

// ============ grep partials + fp16 copy of hidden (for gather) ============
__global__ __launch_bounds__(256) void grep_kernel(const float* __restrict__ h,
                                                   float* __restrict__ partial,
                                                   _Float16* __restrict__ h16) {
    const int c  = threadIdx.x & 63;
    const int rl = threadIdx.x >> 6;
    float acc = 0.f;
    for (int r = blockIdx.x * 4 + rl; r < NN; r += gridDim.x * 4) {
        float v = h[r * H + c];
        h16[r * H + c] = (_Float16)v;
        acc += v;
    }
    __shared__ float s[4][64];
    s[rl][c] = acc;
    __syncthreads();
    if (threadIdx.x < 64)
        partial[blockIdx.x * 64 + threadIdx.x] =
            s[0][threadIdx.x] + s[1][threadIdx.x] +
            s[2][threadIdx.x] + s[3][threadIdx.x];
}

// ============ b1e: reduce partials + fold grep term into layer-1 bias ====
__global__ __launch_bounds__(256) void b1e_kernel(const float* __restrict__ partial,
        const float* __restrict__ W1, const float* __restrict__ b1,
        float* __restrict__ b1e) {
    __shared__ float sg[4][64];
    __shared__ float g[64];
    const int t = threadIdx.x;
    const int c = t & 63, rl = t >> 6;
    float s = 0.f;
    for (int i = rl; i < 256; i += 4) s += partial[i * 64 + c];
    sg[rl][c] = s;
    __syncthreads();
    if (t < 64) g[t] = sg[0][t] + sg[1][t] + sg[2][t] + sg[3][t];
    __syncthreads();
    if (t < 128) {
        float s2 = b1[t];
        for (int k = 0; k < 64; ++k)
            s2 = fmaf(g[k], W1[(128 + k) * 128 + t], s2);
        b1e[t] = s2;
    }
}

// ============ gather from fp16 table: 8 lanes/row x 8 chains ============
__global__ __launch_bounds__(256) void gather_kernel(const _Float16* __restrict__ h16,
                                                     const u16* __restrict__ csr,
                                                     const int* __restrict__ off,
                                                     float* __restrict__ agg) {
    const int wid = blockIdx.x * 4 + (threadIdx.x >> 6);
    if (wid >= NN) return;
    const int lane = threadIdx.x & 63;
    const int g8 = lane >> 3, sub = lane & 7;
    const int beg = off[wid], end = off[wid + 1];
    float a[8] = {0.f, 0.f, 0.f, 0.f, 0.f, 0.f, 0.f, 0.f};
    for (int e = beg + g8; e < end; e += 8) {
        int s = csr[e];
        f16v8 v = *(const f16v8*)&h16[(size_t)s * 64 + sub * 8];
#pragma unroll
        for (int j = 0; j < 8; ++j) a[j] += (float)v[j];
    }
#pragma unroll
    for (int o = 8; o <= 32; o <<= 1) {
#pragma unroll
        for (int j = 0; j < 8; ++j) a[j] += __shfl_xor(a[j], o);
    }
    if (g8 == 0) {
        float4 v0 = {a[0], a[1], a[2], a[3]};
        float4 v1 = {a[4], a[5], a[6], a[7]};
        *(float4*)&agg[(size_t)wid * 64 + sub * 8] = v0;
        *(float4*)&agg[(size_t)wid * 64 + sub * 8 + 4] = v1;
    }
}

// ============ MFMA MLP: 8 waves/block, per-wave col-tile, B hoisted =======
#define MLP_MFMA(d, a, b) d = __builtin_amdgcn_mfma_f32_16x16x32_bf16(a, b, d, 0, 0, 0)

__global__ __launch_bounds__(512, 4) void mlp_mfma(
    const float* __restrict__ agg, const float* __restrict__ hin,
    const float* __restrict__ b1e, const u16* __restrict__ wt,
    const float* __restrict__ b2, const float* __restrict__ b3,
    float* __restrict__ out)
{
    __shared__ u16 hhi[64 * 128], hlo[64 * 128];
    __shared__ float ssw[4 * 64];
    const int t = threadIdx.x;
    const int wl = t >> 6, lane = t & 63;
    const int li = lane & 15, g = lane >> 4;
    const int n0 = blockIdx.x * 64;

    const u16* w1hi = wt;
    const u16* w1lo = wt + 16384;
    const u16* w2hi = wt + 32768;
    const u16* w2lo = wt + 49152;
    const u16* w3hi = wt + 65536;
    const u16* w3lo = wt + 73728;

    // ---- stage x = [agg | hidden]: thread t -> row t>>3, 16 cols ----
    {
        const int row = t >> 3, col0 = (t & 7) * 16;
        const int node = min(n0 + row, NN - 1);
        const float* sp = (col0 < 64) ? (agg + (size_t)node * 64 + col0)
                                      : (hin + (size_t)node * 64 + (col0 - 64));
        float4 u0 = *(const float4*)sp;
        float4 u1 = *(const float4*)(sp + 4);
        float4 u2 = *(const float4*)(sp + 8);
        float4 u3 = *(const float4*)(sp + 12);
        float f[16] = {u0.x, u0.y, u0.z, u0.w, u1.x, u1.y, u1.z, u1.w,
                       u2.x, u2.y, u2.z, u2.w, u3.x, u3.y, u3.z, u3.w};
        s16v8 hv0, lv0, hv1, lv1;
#pragma unroll
        for (int j = 0; j < 8; ++j) {
            u16 hb = f2bf(f[j]);
            hv0[j] = (short)hb;
            lv0[j] = (short)f2bf(f[j] - bf2f(hb));
            u16 hb1 = f2bf(f[8 + j]);
            hv1[j] = (short)hb1;
            lv1[j] = (short)f2bf(f[8 + j] - bf2f(hb1));
        }
        const int cb = col0 >> 3;
        const int a0 = row * 128 + (((cb ^ (row & 7)) << 3));
        const int a1 = row * 128 + ((((cb + 1) ^ (row & 7)) << 3));
        *(s16v8*)&hhi[a0] = hv0; *(s16v8*)&hlo[a0] = lv0;
        *(s16v8*)&hhi[a1] = hv1; *(s16v8*)&hlo[a1] = lv1;
    }
    __syncthreads();

    // ================= L1 (x -> h1) =================
    {
        const int col = wl * 16 + li;
        s16v8 Bh[4], Bl[4];
#pragma unroll
        for (int ks = 0; ks < 4; ++ks) {
            Bh[ks] = *(const s16v8*)(w1hi + col * 128 + ks * 32 + g * 8);
            Bl[ks] = *(const s16v8*)(w1lo + col * 128 + ks * 32 + g * 8);
        }
        f32v4 acc[4];
#pragma unroll
        for (int i = 0; i < 4; ++i) acc[i] = (f32v4){0.f, 0.f, 0.f, 0.f};
#pragma unroll
        for (int rt = 0; rt < 4; ++rt) {
            const int row = rt * 16 + li;
#pragma unroll
            for (int ks = 0; ks < 4; ++ks) {
                const int kb = ks * 4 + g;
                const int addr = row * 128 + ((kb ^ (row & 7)) << 3);
                s16v8 Ah = *(const s16v8*)&hhi[addr];
                s16v8 Al = *(const s16v8*)&hlo[addr];
                MLP_MFMA(acc[rt], Ah, Bh[ks]);
                MLP_MFMA(acc[rt], Ah, Bl[ks]);
                MLP_MFMA(acc[rt], Al, Bh[ks]);
            }
        }
        __syncthreads();                        // all x reads complete
        const float bb = b1e[col];
        const int cb = col >> 3, c7 = col & 7;
#pragma unroll
        for (int rt = 0; rt < 4; ++rt) {
#pragma unroll
            for (int r = 0; r < 4; ++r) {
                float hv = fmaxf(acc[rt][r] + bb, 0.f);
                u16 hb = f2bf(hv);
                u16 lb = f2bf(hv - bf2f(hb));
                const int row = rt * 16 + g * 4 + r;
                const int addr = row * 128 + (((cb ^ (row & 7)) << 3) | c7);
                hhi[addr] = hb; hlo[addr] = lb;
            }
        }
    }
    __syncthreads();

    // ================= L2 (h1 -> h2) =================
    {
        const int col = wl * 16 + li;
        s16v8 Bh[4], Bl[4];
#pragma unroll
        for (int ks = 0; ks < 4; ++ks) {
            Bh[ks] = *(const s16v8*)(w2hi + col * 128 + ks * 32 + g * 8);
            Bl[ks] = *(const s16v8*)(w2lo + col * 128 + ks * 32 + g * 8);
        }
        f32v4 acc[4];
#pragma unroll
        for (int i = 0; i < 4; ++i) acc[i] = (f32v4){0.f, 0.f, 0.f, 0.f};
#pragma unroll
        for (int rt = 0; rt < 4; ++rt) {
            const int row = rt * 16 + li;
#pragma unroll
            for (int ks = 0; ks < 4; ++ks) {
                const int kb = ks * 4 + g;
                const int addr = row * 128 + ((kb ^ (row & 7)) << 3);
                s16v8 Ah = *(const s16v8*)&hhi[addr];
                s16v8 Al = *(const s16v8*)&hlo[addr];
                MLP_MFMA(acc[rt], Ah, Bh[ks]);
                MLP_MFMA(acc[rt], Ah, Bl[ks]);
                MLP_MFMA(acc[rt], Al, Bh[ks]);
            }
        }
        __syncthreads();
        const float bb = b2[col];
        const int cb = col >> 3, c7 = col & 7;
#pragma unroll
        for (int rt = 0; rt < 4; ++rt) {
#pragma unroll
            for (int r = 0; r < 4; ++r) {
                float hv = fmaxf(acc[rt][r] + bb, 0.f);
                u16 hb = f2bf(hv);
                u16 lb = f2bf(hv - bf2f(hb));
                const int row = rt * 16 + g * 4 + r;
                const int addr = row * 128 + (((cb ^ (row & 7)) << 3) | c7);
                hhi[addr] = hb; hlo[addr] = lb;
            }
        }
    }
    __syncthreads();

    // ================= L3 (h2 -> out, waves 0-3) + row L2 norm ============
    float v[4][4];
    if (wl < 4) {
        const int col = wl * 16 + li;
        s16v8 Bh[4], Bl[4];
#pragma unroll
        for (int ks = 0; ks < 4; ++ks) {
            Bh[ks] = *(const s16v8*)(w3hi + col * 128 + ks * 32 + g * 8);
            Bl[ks] = *(const s16v8*)(w3lo + col * 128 + ks * 32 + g * 8);
        }
        f32v4 acc[4];
#pragma unroll
        for (int i = 0; i < 4; ++i) acc[i] = (f32v4){0.f, 0.f, 0.f, 0.f};
#pragma unroll
        for (int rt = 0; rt < 4; ++rt) {
            const int row = rt * 16 + li;
#pragma unroll
            for (int ks = 0; ks < 4; ++ks) {
                const int kb = ks * 4 + g;
                const int addr = row * 128 + ((kb ^ (row & 7)) << 3);
                s16v8 Ah = *(const s16v8*)&hhi[addr];
                s16v8 Al = *(const s16v8*)&hlo[addr];
                MLP_MFMA(acc[rt], Ah, Bh[ks]);
                MLP_MFMA(acc[rt], Ah, Bl[ks]);
                MLP_MFMA(acc[rt], Al, Bh[ks]);
            }
        }
        const float bb = b3[col];
#pragma unroll
        for (int rt = 0; rt < 4; ++rt) {
#pragma unroll
            for (int r = 0; r < 4; ++r) {
                float vv = acc[rt][r] + bb;
                v[rt][r] = vv;
                float s2 = vv * vv;
#pragma unroll
                for (int o = 1; o <= 8; o <<= 1) s2 += __shfl_xor(s2, o);
                if (li == 0) ssw[wl * 64 + rt * 16 + g * 4 + r] = s2;
            }
        }
    }
    __syncthreads();
    if (wl < 4) {
        const int col = wl * 16 + li;
#pragma unroll
        for (int rt = 0; rt < 4; ++rt) {
#pragma unroll
            for (int r = 0; r < 4; ++r) {
                const int row = rt * 16 + g * 4 + r;
                const float tot = ssw[row] + ssw[64 + row] +
                                  ssw[128 + row] + ssw[192 + row];
                const float inv = rsqrtf(tot);
                const int node = n0 + row;
                if (node < NN)
                    out[(size_t)node * 64 + col] = v[rt][r] * inv;
            }
        }
    }
}

// -------------------------------------------------------------------------
extern "C" void kernel_launch(void* const* d_in, const int* in_sizes, int n_in,
                              void* d_out, int out_size, void* d_ws, size_t ws_size,
                              hipStream_t stream) {
    const float* hidden = (const float*)d_in[0];
    const int*   src    = (const int*)d_in[1];
    const int*   dst    = (const int*)d_in[2];
    const float* W1f    = (const float*)d_in[3];
    const float* b1f    = (const float*)d_in[4];
    const float* W2f    = (const float*)d_in[5];
    const float* b2f    = (const float*)d_in[6];
    const float* W3f    = (const float*)d_in[7];
    const float* b3f    = (const float*)d_in[8];

    float* agg     = (float*)d_ws;                        // NN*H
    float* b1e     = agg + (size_t)NN * H;                // 128
    float* partial = b1e + 128;                           // 256*64
    float* hA      = partial + 256 * 64;                  // NN*H
    int*   bbase   = (int*)(hA + (size_t)NN * H);         // NB+1
    int*   off     = bbase + (NB + 1);                    // NN+1
    int*   chist   = off + (NN + 1);                      // NCH*NB
    u32*   bin     = (u32*)(chist + NCH * NB);            // NE
    u16*   csr     = (u16*)(bin + NE);                    // NE
    u16*   wt      = (u16*)(((uintptr_t)(csr + NE) + 255) & ~(uintptr_t)255);
    _Float16* h16  = (_Float16*)(wt + 2 * 81920);         // NN*H fp16

    // ---- one-time per call: bucketized CSR + weight planes ----
    hist_kernel<<<NCH, 256, 0, stream>>>(dst, chist);
    cscan_kernel<<<1, 512, 0, stream>>>(chist, bbase);
    scat_kernel<<<NCH, 256, 0, stream>>>(src, dst, chist, bin);
    binB_kernel<<<NB, 256, 0, stream>>>(bin, bbase, off, csr);
    prep_kernel<<<(2 * 40960 + 255) / 256, 256, 0, stream>>>(W1f, W2f, W3f, wt);

    const float* hin = hidden;
    float* houts[4] = { hA, (float*)d_out, hA, (float*)d_out };

    for (int it = 0; it < 4; ++it) {
        const int blk = it >> 1;
        grep_kernel<<<256, 256, 0, stream>>>(hin, partial, h16);
        b1e_kernel<<<1, 256, 0, stream>>>(partial, W1f + blk * 24576, b1f + blk * 128, b1e);
        gather_kernel<<<(NN + 3) / 4, 256, 0, stream>>>(h16, csr, off, agg);
        mlp_mfma<<<(NN + 63) / 64, 512, 0, stream>>>(agg, hin, b1e, wt + blk * 81920,
            b2f + blk * 128, b3f + blk * 64, houts[it]);
        hin = houts[it];
    }
}